// Round 13
// baseline (244.541 us; speedup 1.0000x reference)
//
#include <hip/hip_runtime.h>
#include <math.h>

#define NB    2
#define NPTS  8192
#define NC    128
#define NKN   16
#define NSPLIT_A 32
#define CSPLIT_A (NPTS / NSPLIT_A)   // 256
#define NSPLIT_B 16
#define CSPLIT_B (NPTS / NSPLIT_B)   // 512
#define BN_EPS 1e-5f

typedef short  v8s __attribute__((ext_vector_type(8)));   // 8 bf16 (4 VGPRs)
typedef float  v4f __attribute__((ext_vector_type(4)));

// fp32 -> bf16 round-to-nearest-even
__device__ __forceinline__ short bf16rne(float f) {
    unsigned u = __float_as_uint(f);
    unsigned r = (u + 0x7FFFu + ((u >> 16) & 1u)) >> 16;
    return (short)r;
}
__device__ __forceinline__ unsigned pack2bf(float a, float b) {
    return (unsigned)(unsigned short)bf16rne(a) | ((unsigned)(unsigned short)bf16rne(b) << 16);
}
__device__ __forceinline__ unsigned cvtpk_bf16(float a, float b) {
    unsigned r;
    asm("v_cvt_pk_bf16_f32 %0, %1, %2" : "=v"(r) : "v"(a), "v"(b));
    return r;
}
__device__ __forceinline__ v8s frag_from4(unsigned u0, unsigned u1, unsigned u2, unsigned u3) {
    union { unsigned u[4]; v8s s; } t;
    t.u[0] = u0; t.u[1] = u1; t.u[2] = u2; t.u[3] = u3;
    return t.s;
}
__device__ __forceinline__ v8s load_wfrag_bf16(const float* __restrict__ wp) {
    float4 f0 = *(const float4*)wp;
    float4 f1 = *(const float4*)(wp + 4);
    return frag_from4(cvtpk_bf16(f0.x, f0.y), cvtpk_bf16(f0.z, f0.w),
                      cvtpk_bf16(f1.x, f1.y), cvtpk_bf16(f1.z, f1.w));
}
__device__ __forceinline__ float bf16_to_f32(unsigned short u) {
    return __uint_as_float(((unsigned)u) << 16);
}

// unconditional sorted-insert into ascending d[0..15], in place (exact merge)
#define INSERTD(XV)                                                  \
  {                                                                  \
    float x_ = (XV);                                                 \
    _Pragma("unroll")                                                \
    for (int s_ = 15; s_ >= 1; s_--)                                 \
      d[s_] = __builtin_amdgcn_fmed3f(d[s_ - 1], d[s_], x_);         \
    d[0] = fminf(d[0], x_);                                          \
  }

// guarded stable sorted-insert of (dist, idx) pairs
#define INSERT16(DV, JV)                                             \
  if ((DV) < ld[15]) {                                               \
    ld[15] = (DV); li[15] = (JV);                                    \
    _Pragma("unroll")                                                \
    for (int s_ = 15; s_ > 0; s_--) {                                \
      bool sw_ = ld[s_] < ld[s_ - 1];                                \
      float da_ = ld[s_ - 1], db_ = ld[s_];                          \
      ld[s_ - 1] = sw_ ? db_ : da_;                                  \
      ld[s_]     = sw_ ? da_ : db_;                                  \
      int ia_ = li[s_ - 1], ib_ = li[s_];                            \
      li[s_ - 1] = sw_ ? ib_ : ia_;                                  \
      li[s_]     = sw_ ? ia_ : ib_;                                  \
    }                                                                \
  }

// reduced ranking metric (per-query constant sqi dropped; fma contraction ok —
// knnF re-verifies with the exact reference formula)
__device__ __forceinline__ float reduced_d(float qx, float qy, float qz, float4 c) {
    float dot = fmaf(qx, c.x, fmaf(qy, c.y, qz * c.z));
    return fmaf(-2.0f, dot, c.w);
}

// ---------------------------------------------------------------------------
// Kernel 1: q/k/v via MFMA. q -> fp32 qT pre-scaled by s1 = bn1g/sqrt(bn1v+e);
// k -> BF16 kTb pre-scaled by s1; v -> BF16 vTb. (unchanged from r12)
// ---------------------------------------------------------------------------
__global__ __launch_bounds__(256) void qkv_kernel(
    const float* __restrict__ x,
    const float* __restrict__ wq, const float* __restrict__ bq,
    const float* __restrict__ wk, const float* __restrict__ bk,
    const float* __restrict__ wv, const float* __restrict__ bv,
    const float* __restrict__ bn1g, const float* __restrict__ bn1v,
    float* __restrict__ qT, unsigned short* __restrict__ kTb,
    unsigned short* __restrict__ vTb)
{
    const int bb = blockIdx.y;
    const int i0 = blockIdx.x * 64;
    const int t  = threadIdx.x;
    const int w  = t >> 6;
    const int l  = t & 63;
    const int lm = l & 15;
    const int lq = l >> 4;

    __shared__ __align__(16) unsigned xspk[64][66];

    #pragma unroll
    for (int kp = w; kp < 64; kp += 4) {
        float v0 = x[((size_t)bb * NC + 2 * kp)     * NPTS + i0 + l];
        float v1 = x[((size_t)bb * NC + 2 * kp + 1) * NPTS + i0 + l];
        xspk[kp][l] = cvtpk_bf16(v0, v1);
    }
    __syncthreads();

    v8s af[4][4];
    #pragma unroll
    for (int Mt = 0; Mt < 4; Mt++) {
        #pragma unroll
        for (int ks = 0; ks < 4; ks++) {
            const int pt  = Mt * 16 + lm;
            const int kp0 = ks * 16 + lq * 4;
            af[Mt][ks] = frag_from4(xspk[kp0][pt], xspk[kp0 + 1][pt],
                                    xspk[kp0 + 2][pt], xspk[kp0 + 3][pt]);
        }
    }

    const int cb = w * 32;
    const float s1a = bn1g[cb + lm]      / sqrtf(bn1v[cb + lm]      + BN_EPS);
    const float s1b = bn1g[cb + 16 + lm] / sqrtf(bn1v[cb + 16 + lm] + BN_EPS);

    const float* Ws[3] = { wq, wk, wv };
    const float* Bs[3] = { bq, bk, bv };

    #pragma unroll
    for (int mat = 0; mat < 3; mat++) {
        const float* __restrict__ W = Ws[mat];
        v8s bfg[2][4];
        #pragma unroll
        for (int nt = 0; nt < 2; nt++)
            #pragma unroll
            for (int ks = 0; ks < 4; ks++)
                bfg[nt][ks] = load_wfrag_bf16(W + (size_t)(cb + nt * 16 + lm) * NC + ks * 32 + lq * 8);
        const float b0 = Bs[mat][cb + lm];
        const float b1 = Bs[mat][cb + 16 + lm];

        v4f acc[4][2];
        #pragma unroll
        for (int Mt = 0; Mt < 4; Mt++) { acc[Mt][0] = (v4f)0.0f; acc[Mt][1] = (v4f)0.0f; }

        #pragma unroll
        for (int Mt = 0; Mt < 4; Mt++)
            #pragma unroll
            for (int ks = 0; ks < 4; ks++) {
                acc[Mt][0] = __builtin_amdgcn_mfma_f32_16x16x32_bf16(af[Mt][ks], bfg[0][ks], acc[Mt][0], 0, 0, 0);
                acc[Mt][1] = __builtin_amdgcn_mfma_f32_16x16x32_bf16(af[Mt][ks], bfg[1][ks], acc[Mt][1], 0, 0, 0);
            }

        #pragma unroll
        for (int Mt = 0; Mt < 4; Mt++)
            #pragma unroll
            for (int nt = 0; nt < 2; nt++) {
                const float bv_ = nt ? b1 : b0;
                const float sc_ = nt ? s1b : s1a;
                #pragma unroll
                for (int r = 0; r < 4; r++) {
                    const size_t off = ((size_t)bb * NPTS + i0 + Mt * 16 + lq * 4 + r) * NC
                                       + cb + nt * 16 + lm;
                    float val = acc[Mt][nt][r] + bv_;
                    if (mat == 0)      qT[off]  = val * sc_;
                    else if (mat == 1) kTb[off] = (unsigned short)bf16rne(val * sc_);
                    else               vTb[off] = (unsigned short)bf16rne(val);
                }
            }
    }
}

// ---------------------------------------------------------------------------
// Kernel 2a: kNN phase A (unchanged)
// ---------------------------------------------------------------------------
__global__ __launch_bounds__(256) void knnA_kernel(
    const float* __restrict__ p,
    float* __restrict__ partd)
{
    const int bb = blockIdx.z, sp = blockIdx.y, q0 = blockIdx.x * 512;
    const int t  = threadIdx.x;

    __shared__ float4 cand[CSPLIT_A];
    const float* __restrict__ pc = p + ((size_t)bb * NPTS + sp * CSPLIT_A) * 3;
    if (t < CSPLIT_A) {
        float cx = pc[t * 3 + 0], cy = pc[t * 3 + 1], cz = pc[t * 3 + 2];
        float s  = fmaf(cx, cx, fmaf(cy, cy, cz * cz));
        cand[t] = make_float4(cx, cy, cz, s);
    }
    __syncthreads();

    const int iA = q0 + t, iB = q0 + 256 + t;
    const float qAx = p[((size_t)bb * NPTS + iA) * 3 + 0];
    const float qAy = p[((size_t)bb * NPTS + iA) * 3 + 1];
    const float qAz = p[((size_t)bb * NPTS + iA) * 3 + 2];
    const float qBx = p[((size_t)bb * NPTS + iB) * 3 + 0];
    const float qBy = p[((size_t)bb * NPTS + iB) * 3 + 1];
    const float qBz = p[((size_t)bb * NPTS + iB) * 3 + 2];

    float dA[4][2], dB[4][2];
    #pragma unroll
    for (int s = 0; s < 4; s++) {
        dA[s][0] = 3.4e38f; dA[s][1] = 3.4e38f;
        dB[s][0] = 3.4e38f; dB[s][1] = 3.4e38f;
    }

    #pragma unroll 2
    for (int j = 0; j < CSPLIT_A; j += 4) {
        #pragma unroll
        for (int s = 0; s < 4; s++) {
            float4 c = cand[j + s];
            float ddA = reduced_d(qAx, qAy, qAz, c);
            dA[s][1] = __builtin_amdgcn_fmed3f(dA[s][0], dA[s][1], ddA);
            dA[s][0] = fminf(dA[s][0], ddA);
            float ddB = reduced_d(qBx, qBy, qBz, c);
            dB[s][1] = __builtin_amdgcn_fmed3f(dB[s][0], dB[s][1], ddB);
            dB[s][0] = fminf(dB[s][0], ddB);
        }
    }

    float* __restrict__ rowA = partd + (((size_t)bb * NSPLIT_A + sp) * NPTS + iA) * 8;
    float* __restrict__ rowB = partd + (((size_t)bb * NSPLIT_A + sp) * NPTS + iB) * 8;
    *(float4*)&rowA[0] = make_float4(dA[0][0], dA[0][1], dA[1][0], dA[1][1]);
    *(float4*)&rowA[4] = make_float4(dA[2][0], dA[2][1], dA[3][0], dA[3][1]);
    *(float4*)&rowB[0] = make_float4(dB[0][0], dB[0][1], dB[1][0], dB[1][1]);
    *(float4*)&rowB[4] = make_float4(dB[2][0], dB[2][1], dB[3][0], dB[3][1]);
}

// ---------------------------------------------------------------------------
// Kernel 2b: threshold merge (unchanged)
// ---------------------------------------------------------------------------
__global__ __launch_bounds__(256) void knnM_kernel(
    const float* __restrict__ partd,
    float* __restrict__ thr)
{
    const int gid = blockIdx.x * 256 + threadIdx.x;
    const int bb  = gid >> 13;
    const int i   = gid & (NPTS - 1);

    float d[16];
    #pragma unroll
    for (int s = 0; s < 16; s++) d[s] = 3.4e38f;

    for (int sp = 0; sp < NSPLIT_A; sp++) {
        const float* __restrict__ r = partd + (((size_t)bb * NSPLIT_A + sp) * NPTS + i) * 8;
        float4 v0 = *(const float4*)&r[0];
        float4 v1 = *(const float4*)&r[4];
        INSERTD(v0.x); INSERTD(v0.y); INSERTD(v0.z); INSERTD(v0.w);
        INSERTD(v1.x); INSERTD(v1.y); INSERTD(v1.z); INSERTD(v1.w);
    }
    thr[gid] = d[15] + (4e-5f + 1e-5f * fabsf(d[15]));
}

// ---------------------------------------------------------------------------
// Kernel 2c: threshold re-scan (unchanged)
// ---------------------------------------------------------------------------
__global__ __launch_bounds__(256) void knnB_kernel(
    const float* __restrict__ p,
    const float* __restrict__ thr,
    int* __restrict__ pidx,
    unsigned* __restrict__ pcnt)
{
    const int bb = blockIdx.z, sp = blockIdx.y, q0 = blockIdx.x * 256;
    const int t  = threadIdx.x;

    __shared__ float4 cand[CSPLIT_B];
    const float* __restrict__ pc = p + ((size_t)bb * NPTS + sp * CSPLIT_B) * 3;
    for (int j = t; j < CSPLIT_B; j += 256) {
        float cx = pc[j * 3 + 0], cy = pc[j * 3 + 1], cz = pc[j * 3 + 2];
        float s  = fmaf(cx, cx, fmaf(cy, cy, cz * cz));
        cand[j] = make_float4(cx, cy, cz, s);
    }
    __syncthreads();

    const int i = q0 + t;
    const float qx = p[((size_t)bb * NPTS + i) * 3 + 0];
    const float qy = p[((size_t)bb * NPTS + i) * 3 + 1];
    const float qz = p[((size_t)bb * NPTS + i) * 3 + 2];
    const float thv = thr[bb * NPTS + i];

    int cnt = 0;
    int* __restrict__ row = pidx + (((size_t)bb * NSPLIT_B + sp) * NPTS + i) * 16;
    #pragma unroll 4
    for (int j = 0; j < CSPLIT_B; j++) {
        float dd = reduced_d(qx, qy, qz, cand[j]);
        if (dd <= thv) {
            if (cnt < 16) row[cnt] = sp * CSPLIT_B + j;
            cnt++;
        }
    }
    pcnt[((size_t)bb * NSPLIT_B + sp) * NPTS + i] = (unsigned)cnt;
}

// ---------------------------------------------------------------------------
// Kernel 2d: finalize (unchanged)
// ---------------------------------------------------------------------------
__global__ __launch_bounds__(256) void knnF_kernel(
    const float* __restrict__ p,
    const int* __restrict__ pidx,
    const unsigned* __restrict__ pcnt,
    int* __restrict__ knn_idx)
{
    const int gid = blockIdx.x * 256 + threadIdx.x;
    const int bb  = gid >> 13;
    const int i   = gid & (NPTS - 1);

    int cnts[NSPLIT_B];
    int total = 0, mx = 0;
    #pragma unroll
    for (int sp = 0; sp < NSPLIT_B; sp++) {
        cnts[sp] = (int)pcnt[((size_t)bb * NSPLIT_B + sp) * NPTS + i];
        total += cnts[sp];
        mx = max(mx, cnts[sp]);
    }
    int* __restrict__ out = knn_idx + (size_t)gid * 16;

    if (mx <= 16 && total == 16) {
        int w = 0;
        for (int sp = 0; sp < NSPLIT_B; sp++) {
            const int* __restrict__ r = pidx + (((size_t)bb * NSPLIT_B + sp) * NPTS + i) * 16;
            for (int e = 0; e < cnts[sp]; e++) out[w++] = r[e];
        }
        return;
    }

    const float qx = p[((size_t)bb * NPTS + i) * 3 + 0];
    const float qy = p[((size_t)bb * NPTS + i) * 3 + 1];
    const float qz = p[((size_t)bb * NPTS + i) * 3 + 2];
    const float sqi = __fadd_rn(__fadd_rn(__fmul_rn(qx, qx), __fmul_rn(qy, qy)),
                                __fmul_rn(qz, qz));
    float ld[16];
    int   li[16];
    #pragma unroll
    for (int s = 0; s < 16; s++) { ld[s] = 3.4e38f; li[s] = 0; }

    if (mx <= 16) {
        for (int sp = 0; sp < NSPLIT_B; sp++) {
            const int* __restrict__ r = pidx + (((size_t)bb * NSPLIT_B + sp) * NPTS + i) * 16;
            for (int e = 0; e < cnts[sp]; e++) {
                int j = r[e];
                float cx = p[((size_t)bb * NPTS + j) * 3 + 0];
                float cy = p[((size_t)bb * NPTS + j) * 3 + 1];
                float cz = p[((size_t)bb * NPTS + j) * 3 + 2];
                float sqj = __fadd_rn(__fadd_rn(__fmul_rn(cx, cx), __fmul_rn(cy, cy)),
                                      __fmul_rn(cz, cz));
                float dot = __fadd_rn(__fadd_rn(__fmul_rn(qx, cx), __fmul_rn(qy, cy)),
                                      __fmul_rn(qz, cz));
                float d2 = __fsub_rn(__fadd_rn(sqi, sqj), __fmul_rn(2.0f, dot));
                INSERT16(d2, j);
            }
        }
    } else {
        for (int j = 0; j < NPTS; j++) {
            float cx = p[((size_t)bb * NPTS + j) * 3 + 0];
            float cy = p[((size_t)bb * NPTS + j) * 3 + 1];
            float cz = p[((size_t)bb * NPTS + j) * 3 + 2];
            float sqj = __fadd_rn(__fadd_rn(__fmul_rn(cx, cx), __fmul_rn(cy, cy)),
                                  __fmul_rn(cz, cz));
            float dot = __fadd_rn(__fadd_rn(__fmul_rn(qx, cx), __fmul_rn(qy, cy)),
                                  __fmul_rn(qz, cz));
            float d2 = __fsub_rn(__fadd_rn(sqi, sqj), __fmul_rn(2.0f, dot));
            INSERT16(d2, j);
        }
    }
    #pragma unroll
    for (int s = 0; s < 16; s++) out[s] = li[s];
}

// ---------------------------------------------------------------------------
// Kernel 3: fused PE-MLP + attention MLP (bf16 MFMA) + softmax + weighted sum.
// r13 change: 4 points/block (was 8) — LDS 39.4 -> ~22 KB, 4 -> 7 blocks/CU,
// occupancy cap 50% -> 87%. Per-thread structure identical (ct loop 8 -> 4).
// grid (NPTS/4, NB), block 256.
// ---------------------------------------------------------------------------
__global__ __launch_bounds__(256) void attn_kernel(
    const float* __restrict__ p,
    const float* __restrict__ qT, const unsigned short* __restrict__ kTb,
    const unsigned short* __restrict__ vTb,
    const int*   __restrict__ knn_idx,
    const float* __restrict__ pe_w1,
    const float* __restrict__ pe_bn_g, const float* __restrict__ pe_bn_b,
    const float* __restrict__ pe_bn_m, const float* __restrict__ pe_bn_v,
    const float* __restrict__ pe_w2, const float* __restrict__ pe_b2,
    const float* __restrict__ bn1g, const float* __restrict__ bn1b,
    const float* __restrict__ bn1m, const float* __restrict__ bn1v,
    const float* __restrict__ at_w1,
    const float* __restrict__ bn2g, const float* __restrict__ bn2b,
    const float* __restrict__ bn2m, const float* __restrict__ bn2v,
    const float* __restrict__ at_w2, const float* __restrict__ at_b2,
    float* __restrict__ y)
{
    // bijective XCD swizzle: grid.x = 2048 (divisible by 8)
    const int bx = (blockIdx.x & 7) * (NPTS / 4 / 8) + (blockIdx.x >> 3);
    const int bb = blockIdx.y;
    const int i0 = bx * 4;
    const int t  = threadIdx.x;
    const int w  = t >> 6;
    const int l  = t & 63;
    const int lm = t & 15;
    const int lq = l >> 4;

    __shared__ __align__(16) unsigned short a1s[64 * 128];   // 16 KB bf16 [col][ch^swz]
    __shared__ __align__(16) float hbuf[3][64];
    __shared__ __align__(16) int   nidx[64];
    __shared__ __align__(16) float sc1[128], sh1[128], sc2[128], sh2[128];
    __shared__ __align__(16) float pw2t[3][128], pb2s[128], ab2s[128];

    float* __restrict__ ybuf = (float*)a1s;   // [128][12] overlay for epilogue

    if (t < 128) {
        int c = t;
        float s1 = bn1g[c] / sqrtf(bn1v[c] + BN_EPS);
        sc1[c] = s1; sh1[c] = bn1b[c] - bn1m[c] * s1;
        float s2 = bn2g[c] / sqrtf(bn2v[c] + BN_EPS);
        sc2[c] = s2; sh2[c] = bn2b[c] - bn2m[c] * s2;
        pw2t[0][c] = pe_w2[c * 3 + 0];
        pw2t[1][c] = pe_w2[c * 3 + 1];
        pw2t[2][c] = pe_w2[c * 3 + 2];
        pb2s[c] = pe_b2[c];
        ab2s[c] = at_b2[c];
    } else if (t < 192) {
        int e = t - 128;
        nidx[e] = knn_idx[(bb * NPTS + i0 + (e >> 4)) * 16 + (e & 15)];
    }
    __syncthreads();

    if (t < 64) {
        int pt = t >> 4;
        int j = nidx[t];
        float pix = p[((size_t)bb * NPTS + i0 + pt) * 3 + 0];
        float piy = p[((size_t)bb * NPTS + i0 + pt) * 3 + 1];
        float piz = p[((size_t)bb * NPTS + i0 + pt) * 3 + 2];
        float rx = p[((size_t)bb * NPTS + j) * 3 + 0] - pix;
        float ry = p[((size_t)bb * NPTS + j) * 3 + 1] - piy;
        float rz = p[((size_t)bb * NPTS + j) * 3 + 2] - piz;
        #pragma unroll
        for (int o = 0; o < 3; o++) {
            float hv = pe_w1[o * 3 + 0] * rx + pe_w1[o * 3 + 1] * ry + pe_w1[o * 3 + 2] * rz;
            float sc = pe_bn_g[o] / sqrtf(pe_bn_v[o] + BN_EPS);
            float sh = pe_bn_b[o] - pe_bn_m[o] * sc;
            hbuf[o][t] = fmaxf(hv * sc + sh, 0.0f);
        }
    }
    __syncthreads();

    // ---- phase 1: a1 = relu(q' - k' + nr') -> bf16 LDS (swizzled), 64 cols ----
    {
        const int c0 = 2 * l, c1 = 2 * l + 1;
        const float s1a = sc1[c0], s1b = sc1[c1];
        const float pa0 = pw2t[0][c0] * s1a, pa1 = pw2t[1][c0] * s1a, pa2 = pw2t[2][c0] * s1a;
        const float pda = pb2s[c0] * s1a + sh1[c0];
        const float pb0 = pw2t[0][c1] * s1b, pb1 = pw2t[1][c1] * s1b, pb2_ = pw2t[2][c1] * s1b;
        const float pdb = pb2s[c1] * s1b + sh1[c1];
        unsigned* a1u = (unsigned*)a1s;
        for (int it = 0; it < 16; ++it) {
            int col = w + 4 * it;
            int pt  = col >> 4;
            int j   = nidx[col];
            float2 qv2 = *(const float2*)&qT[((size_t)(bb * NPTS + i0 + pt)) * NC + c0];
            unsigned ku = *(const unsigned*)&kTb[((size_t)(bb * NPTS + j)) * NC + c0];
            float k0 = __uint_as_float(ku << 16);
            float k1 = __uint_as_float(ku & 0xffff0000u);
            float h0 = hbuf[0][col], h1 = hbuf[1][col], h2 = hbuf[2][col];
            float nra = fmaf(pa0, h0, fmaf(pa1, h1, fmaf(pa2, h2, pda)));
            float nrb = fmaf(pb0, h0, fmaf(pb1, h1, fmaf(pb2_, h2, pdb)));
            float a0 = fmaxf(qv2.x - k0 + nra, 0.0f);
            float a1v = fmaxf(qv2.y - k1 + nrb, 0.0f);
            a1u[col * 64 + (l ^ ((col & 7) << 2))] = pack2bf(a0, a1v);
        }
    }

    v8s wf[2][4];
    #pragma unroll
    for (int rt = 0; rt < 2; rt++)
        #pragma unroll
        for (int ks = 0; ks < 4; ks++)
            wf[rt][ks] = load_wfrag_bf16(at_w1 + (size_t)(w * 32 + rt * 16 + lm) * NC + ks * 32 + lq * 8);

    __syncthreads();

    v4f acc[2][4];
    #pragma unroll
    for (int rt = 0; rt < 2; rt++)
        #pragma unroll
        for (int ct = 0; ct < 4; ct++) acc[rt][ct] = (v4f)0.0f;

    #pragma unroll
    for (int ct = 0; ct < 4; ct++) {
        const int col = ct * 16 + lm;
        const int sw8 = (col & 7) << 3;
        #pragma unroll
        for (int ks = 0; ks < 4; ks++) {
            v8s b = *(const v8s*)&a1s[col * 128 + ((ks * 32 + lq * 8) ^ sw8)];
            acc[0][ct] = __builtin_amdgcn_mfma_f32_16x16x32_bf16(wf[0][ks], b, acc[0][ct], 0, 0, 0);
            acc[1][ct] = __builtin_amdgcn_mfma_f32_16x16x32_bf16(wf[1][ks], b, acc[1][ct], 0, 0, 0);
        }
    }
    __syncthreads();

    #pragma unroll
    for (int rt = 0; rt < 2; rt++) {
        const int r0 = w * 32 + rt * 16 + lq * 4;
        float4 scv = *(const float4*)&sc2[r0];
        float4 shv = *(const float4*)&sh2[r0];
        #pragma unroll
        for (int ct = 0; ct < 4; ct++) {
            const int col = ct * 16 + lm;
            v4f v = acc[rt][ct];
            float x0 = fmaxf(v[0] * scv.x + shv.x, 0.0f);
            float x1 = fmaxf(v[1] * scv.y + shv.y, 0.0f);
            float x2 = fmaxf(v[2] * scv.z + shv.z, 0.0f);
            float x3 = fmaxf(v[3] * scv.w + shv.w, 0.0f);
            *(uint2*)&a1s[col * 128 + (r0 ^ ((col & 7) << 3))] =
                make_uint2(pack2bf(x0, x1), pack2bf(x2, x3));
        }
    }

    #pragma unroll
    for (int rt = 0; rt < 2; rt++)
        #pragma unroll
        for (int ks = 0; ks < 4; ks++)
            wf[rt][ks] = load_wfrag_bf16(at_w2 + (size_t)(w * 32 + rt * 16 + lm) * NC + ks * 32 + lq * 8);

    __syncthreads();

    #pragma unroll
    for (int rt = 0; rt < 2; rt++)
        #pragma unroll
        for (int ct = 0; ct < 4; ct++) acc[rt][ct] = (v4f)0.0f;

    #pragma unroll
    for (int ct = 0; ct < 4; ct++) {
        const int col = ct * 16 + lm;
        const int sw8 = (col & 7) << 3;
        #pragma unroll
        for (int ks = 0; ks < 4; ks++) {
            v8s b = *(const v8s*)&a1s[col * 128 + ((ks * 32 + lq * 8) ^ sw8)];
            acc[0][ct] = __builtin_amdgcn_mfma_f32_16x16x32_bf16(b, wf[0][ks], acc[0][ct], 0, 0, 0);
            acc[1][ct] = __builtin_amdgcn_mfma_f32_16x16x32_bf16(b, wf[1][ks], acc[1][ct], 0, 0, 0);
        }
    }
    __syncthreads();

    #pragma unroll
    for (int ct = 0; ct < 4; ct++) {
        const int colb = ct * 16 + lq * 4;
        float4 h0 = *(const float4*)&hbuf[0][colb];
        float4 h1 = *(const float4*)&hbuf[1][colb];
        float4 h2 = *(const float4*)&hbuf[2][colb];
        int j0 = nidx[colb + 0], j1 = nidx[colb + 1];
        int j2 = nidx[colb + 2], j3 = nidx[colb + 3];
        #pragma unroll
        for (int rt = 0; rt < 2; rt++) {
            const int c = w * 32 + rt * 16 + lm;
            const float pw0 = pw2t[0][c], pw1 = pw2t[1][c], pw2v = pw2t[2][c];
            const float pb = pb2s[c], b2 = ab2s[c];
            v4f lg = acc[rt][ct];
            float v0 = bf16_to_f32(vTb[((size_t)(bb * NPTS + j0)) * NC + c]);
            float v1 = bf16_to_f32(vTb[((size_t)(bb * NPTS + j1)) * NC + c]);
            float v2 = bf16_to_f32(vTb[((size_t)(bb * NPTS + j2)) * NC + c]);
            float v3 = bf16_to_f32(vTb[((size_t)(bb * NPTS + j3)) * NC + c]);
            float e0 = __expf(lg[0] + b2);
            float e1 = __expf(lg[1] + b2);
            float e2 = __expf(lg[2] + b2);
            float e3 = __expf(lg[3] + b2);
            float n0 = pw0 * h0.x + pw1 * h1.x + pw2v * h2.x + pb;
            float n1 = pw0 * h0.y + pw1 * h1.y + pw2v * h2.y + pb;
            float n2 = pw0 * h0.z + pw1 * h1.z + pw2v * h2.z + pb;
            float n3 = pw0 * h0.w + pw1 * h1.w + pw2v * h2.w + pb;
            float se = (e0 + e1) + (e2 + e3);
            float pr = (e0 * (v0 + n0) + e1 * (v1 + n1)) + (e2 * (v2 + n2) + e3 * (v3 + n3));
            se += __shfl_xor(se, 16); pr += __shfl_xor(pr, 16);
            se += __shfl_xor(se, 32); pr += __shfl_xor(pr, 32);
            if (lq == 0) ybuf[c * 12 + ct] = pr / se;
        }
    }
    __syncthreads();

    if (t < 128) {
        float4 o = *(const float4*)&ybuf[t * 12];
        *(float4*)&y[((size_t)bb * NC + t) * NPTS + i0] = o;
    }
}

// ---------------------------------------------------------------------------
extern "C" void kernel_launch(void* const* d_in, const int* in_sizes, int n_in,
                              void* d_out, int out_size, void* d_ws, size_t ws_size,
                              hipStream_t stream) {
    const float* p     = (const float*)d_in[0];
    const float* x     = (const float*)d_in[1];
    const float* wq    = (const float*)d_in[2];
    const float* bq    = (const float*)d_in[3];
    const float* wk    = (const float*)d_in[4];
    const float* bk    = (const float*)d_in[5];
    const float* wv    = (const float*)d_in[6];
    const float* bv    = (const float*)d_in[7];
    const float* pe_w1 = (const float*)d_in[8];
    const float* pe_bn_g = (const float*)d_in[9];
    const float* pe_bn_b = (const float*)d_in[10];
    const float* pe_bn_m = (const float*)d_in[11];
    const float* pe_bn_v = (const float*)d_in[12];
    const float* pe_w2 = (const float*)d_in[13];
    const float* pe_b2 = (const float*)d_in[14];
    const float* bn1g  = (const float*)d_in[15];
    const float* bn1b  = (const float*)d_in[16];
    const float* bn1m  = (const float*)d_in[17];
    const float* bn1v  = (const float*)d_in[18];
    const float* at_w1 = (const float*)d_in[19];
    const float* bn2g  = (const float*)d_in[20];
    const float* bn2b  = (const float*)d_in[21];
    const float* bn2m  = (const float*)d_in[22];
    const float* bn2v  = (const float*)d_in[23];
    const float* at_w2 = (const float*)d_in[24];
    const float* at_b2 = (const float*)d_in[25];
    float* out = (float*)d_out;

    // workspace (25 MB): [idx 1MB][X: 24MB]
    //   final tensors (written by qkv, after ALL kNN kernels):
    //     qT  fp32 @ X (8MB, s1-scaled) | kTb bf16 @ X+8MB (4MB, s1-scaled)
    //     vTb bf16 @ X+12MB (4MB)
    //   kNN scratch (all consumed before qkv):
    //     partd @ X (16.8MB) | pidx @ X (16.8MB, after knnM) |
    //     pcnt @ X+18MB (1.05MB) | thr @ X+22MB (64KB)
    char* base = (char*)d_ws;
    int*   idx   = (int*)base;
    char*  X     = base + (1u << 20);
    float* qT    = (float*)X;
    unsigned short* kTb = (unsigned short*)(X + (size_t)8 * (1u << 20));
    unsigned short* vTb = (unsigned short*)(X + (size_t)12 * (1u << 20));
    float* partd = (float*)X;
    int*   pidx  = (int*)X;
    unsigned* pcnt = (unsigned*)(X + (size_t)18 * (1u << 20));
    float* thr   = (float*)(X + (size_t)22 * (1u << 20));

    knnA_kernel<<<dim3(NPTS / 512, NSPLIT_A, NB), 256, 0, stream>>>(p, partd);
    knnM_kernel<<<dim3(NB * NPTS / 256), 256, 0, stream>>>(partd, thr);
    knnB_kernel<<<dim3(NPTS / 256, NSPLIT_B, NB), 256, 0, stream>>>(p, thr, pidx, pcnt);
    knnF_kernel<<<dim3(NB * NPTS / 256), 256, 0, stream>>>(p, pidx, pcnt, idx);
    qkv_kernel<<<dim3(NPTS / 64, NB), 256, 0, stream>>>(
        x, wq, bq, wk, bk, wv, bv, bn1g, bn1v, qT, kTb, vTb);
    attn_kernel<<<dim3(NPTS / 4, NB), 256, 0, stream>>>(
        p, qT, kTb, vTb, idx,
        pe_w1, pe_bn_g, pe_bn_b, pe_bn_m, pe_bn_v, pe_w2, pe_b2,
        bn1g, bn1b, bn1m, bn1v, at_w1,
        bn2g, bn2b, bn2m, bn2v, at_w2, at_b2, out);
}

// Round 14
// 224.106 us; speedup vs baseline: 1.0912x; 1.0912x over previous
//
#include <hip/hip_runtime.h>
#include <math.h>

#define NB    2
#define NPTS  8192
#define NC    128
#define NKN   16
#define NSPLIT_A 32
#define CSPLIT_A (NPTS / NSPLIT_A)   // 256
#define NSPLIT_B 16
#define CSPLIT_B (NPTS / NSPLIT_B)   // 512
#define BN_EPS 1e-5f

typedef short  v8s __attribute__((ext_vector_type(8)));   // 8 bf16 (4 VGPRs)
typedef float  v4f __attribute__((ext_vector_type(4)));

// fp32 -> bf16 round-to-nearest-even
__device__ __forceinline__ short bf16rne(float f) {
    unsigned u = __float_as_uint(f);
    unsigned r = (u + 0x7FFFu + ((u >> 16) & 1u)) >> 16;
    return (short)r;
}
__device__ __forceinline__ unsigned pack2bf(float a, float b) {
    return (unsigned)(unsigned short)bf16rne(a) | ((unsigned)(unsigned short)bf16rne(b) << 16);
}
__device__ __forceinline__ unsigned cvtpk_bf16(float a, float b) {
    unsigned r;
    asm("v_cvt_pk_bf16_f32 %0, %1, %2" : "=v"(r) : "v"(a), "v"(b));
    return r;
}
__device__ __forceinline__ v8s frag_from4(unsigned u0, unsigned u1, unsigned u2, unsigned u3) {
    union { unsigned u[4]; v8s s; } t;
    t.u[0] = u0; t.u[1] = u1; t.u[2] = u2; t.u[3] = u3;
    return t.s;
}
__device__ __forceinline__ v8s load_wfrag_bf16(const float* __restrict__ wp) {
    float4 f0 = *(const float4*)wp;
    float4 f1 = *(const float4*)(wp + 4);
    return frag_from4(cvtpk_bf16(f0.x, f0.y), cvtpk_bf16(f0.z, f0.w),
                      cvtpk_bf16(f1.x, f1.y), cvtpk_bf16(f1.z, f1.w));
}
__device__ __forceinline__ float bf16_to_f32(unsigned short u) {
    return __uint_as_float(((unsigned)u) << 16);
}

// unconditional sorted-insert into ascending d[0..15], in place (exact merge)
#define INSERTD(XV)                                                  \
  {                                                                  \
    float x_ = (XV);                                                 \
    _Pragma("unroll")                                                \
    for (int s_ = 15; s_ >= 1; s_--)                                 \
      d[s_] = __builtin_amdgcn_fmed3f(d[s_ - 1], d[s_], x_);         \
    d[0] = fminf(d[0], x_);                                          \
  }

// guarded stable sorted-insert of (dist, idx) pairs
#define INSERT16(DV, JV)                                             \
  if ((DV) < ld[15]) {                                               \
    ld[15] = (DV); li[15] = (JV);                                    \
    _Pragma("unroll")                                                \
    for (int s_ = 15; s_ > 0; s_--) {                                \
      bool sw_ = ld[s_] < ld[s_ - 1];                                \
      float da_ = ld[s_ - 1], db_ = ld[s_];                          \
      ld[s_ - 1] = sw_ ? db_ : da_;                                  \
      ld[s_]     = sw_ ? da_ : db_;                                  \
      int ia_ = li[s_ - 1], ib_ = li[s_];                            \
      li[s_ - 1] = sw_ ? ib_ : ia_;                                  \
      li[s_]     = sw_ ? ia_ : ib_;                                  \
    }                                                                \
  }

// reduced ranking metric (per-query constant sqi dropped; fma contraction ok —
// knnF re-verifies with the exact reference formula)
__device__ __forceinline__ float reduced_d(float qx, float qy, float qz, float4 c) {
    float dot = fmaf(qx, c.x, fmaf(qy, c.y, qz * c.z));
    return fmaf(-2.0f, dot, c.w);
}

// ---------------------------------------------------------------------------
// Kernel 1: q/k/v via MFMA. q -> fp32 qT pre-scaled by s1 = bn1g/sqrt(bn1v+e);
// k -> BF16 kTb pre-scaled by s1; v -> BF16 vTb.
// ---------------------------------------------------------------------------
__global__ __launch_bounds__(256) void qkv_kernel(
    const float* __restrict__ x,
    const float* __restrict__ wq, const float* __restrict__ bq,
    const float* __restrict__ wk, const float* __restrict__ bk,
    const float* __restrict__ wv, const float* __restrict__ bv,
    const float* __restrict__ bn1g, const float* __restrict__ bn1v,
    float* __restrict__ qT, unsigned short* __restrict__ kTb,
    unsigned short* __restrict__ vTb)
{
    const int bb = blockIdx.y;
    const int i0 = blockIdx.x * 64;
    const int t  = threadIdx.x;
    const int w  = t >> 6;
    const int l  = t & 63;
    const int lm = l & 15;
    const int lq = l >> 4;

    __shared__ __align__(16) unsigned xspk[64][66];

    #pragma unroll
    for (int kp = w; kp < 64; kp += 4) {
        float v0 = x[((size_t)bb * NC + 2 * kp)     * NPTS + i0 + l];
        float v1 = x[((size_t)bb * NC + 2 * kp + 1) * NPTS + i0 + l];
        xspk[kp][l] = cvtpk_bf16(v0, v1);
    }
    __syncthreads();

    v8s af[4][4];
    #pragma unroll
    for (int Mt = 0; Mt < 4; Mt++) {
        #pragma unroll
        for (int ks = 0; ks < 4; ks++) {
            const int pt  = Mt * 16 + lm;
            const int kp0 = ks * 16 + lq * 4;
            af[Mt][ks] = frag_from4(xspk[kp0][pt], xspk[kp0 + 1][pt],
                                    xspk[kp0 + 2][pt], xspk[kp0 + 3][pt]);
        }
    }

    const int cb = w * 32;
    const float s1a = bn1g[cb + lm]      / sqrtf(bn1v[cb + lm]      + BN_EPS);
    const float s1b = bn1g[cb + 16 + lm] / sqrtf(bn1v[cb + 16 + lm] + BN_EPS);

    const float* Ws[3] = { wq, wk, wv };
    const float* Bs[3] = { bq, bk, bv };

    #pragma unroll
    for (int mat = 0; mat < 3; mat++) {
        const float* __restrict__ W = Ws[mat];
        v8s bfg[2][4];
        #pragma unroll
        for (int nt = 0; nt < 2; nt++)
            #pragma unroll
            for (int ks = 0; ks < 4; ks++)
                bfg[nt][ks] = load_wfrag_bf16(W + (size_t)(cb + nt * 16 + lm) * NC + ks * 32 + lq * 8);
        const float b0 = Bs[mat][cb + lm];
        const float b1 = Bs[mat][cb + 16 + lm];

        v4f acc[4][2];
        #pragma unroll
        for (int Mt = 0; Mt < 4; Mt++) { acc[Mt][0] = (v4f)0.0f; acc[Mt][1] = (v4f)0.0f; }

        #pragma unroll
        for (int Mt = 0; Mt < 4; Mt++)
            #pragma unroll
            for (int ks = 0; ks < 4; ks++) {
                acc[Mt][0] = __builtin_amdgcn_mfma_f32_16x16x32_bf16(af[Mt][ks], bfg[0][ks], acc[Mt][0], 0, 0, 0);
                acc[Mt][1] = __builtin_amdgcn_mfma_f32_16x16x32_bf16(af[Mt][ks], bfg[1][ks], acc[Mt][1], 0, 0, 0);
            }

        #pragma unroll
        for (int Mt = 0; Mt < 4; Mt++)
            #pragma unroll
            for (int nt = 0; nt < 2; nt++) {
                const float bv_ = nt ? b1 : b0;
                const float sc_ = nt ? s1b : s1a;
                #pragma unroll
                for (int r = 0; r < 4; r++) {
                    const size_t off = ((size_t)bb * NPTS + i0 + Mt * 16 + lq * 4 + r) * NC
                                       + cb + nt * 16 + lm;
                    float val = acc[Mt][nt][r] + bv_;
                    if (mat == 0)      qT[off]  = val * sc_;
                    else if (mat == 1) kTb[off] = (unsigned short)bf16rne(val * sc_);
                    else               vTb[off] = (unsigned short)bf16rne(val);
                }
            }
    }
}

// ---------------------------------------------------------------------------
// Kernel 2a: kNN phase A — 4 sorted-2 sublists per (query, split), reduced
// metric, 6 VALU ops/candidate. 2 queries/thread.
// ---------------------------------------------------------------------------
__global__ __launch_bounds__(256) void knnA_kernel(
    const float* __restrict__ p,
    float* __restrict__ partd)
{
    const int bb = blockIdx.z, sp = blockIdx.y, q0 = blockIdx.x * 512;
    const int t  = threadIdx.x;

    __shared__ float4 cand[CSPLIT_A];
    const float* __restrict__ pc = p + ((size_t)bb * NPTS + sp * CSPLIT_A) * 3;
    if (t < CSPLIT_A) {
        float cx = pc[t * 3 + 0], cy = pc[t * 3 + 1], cz = pc[t * 3 + 2];
        float s  = fmaf(cx, cx, fmaf(cy, cy, cz * cz));
        cand[t] = make_float4(cx, cy, cz, s);
    }
    __syncthreads();

    const int iA = q0 + t, iB = q0 + 256 + t;
    const float qAx = p[((size_t)bb * NPTS + iA) * 3 + 0];
    const float qAy = p[((size_t)bb * NPTS + iA) * 3 + 1];
    const float qAz = p[((size_t)bb * NPTS + iA) * 3 + 2];
    const float qBx = p[((size_t)bb * NPTS + iB) * 3 + 0];
    const float qBy = p[((size_t)bb * NPTS + iB) * 3 + 1];
    const float qBz = p[((size_t)bb * NPTS + iB) * 3 + 2];

    float dA[4][2], dB[4][2];
    #pragma unroll
    for (int s = 0; s < 4; s++) {
        dA[s][0] = 3.4e38f; dA[s][1] = 3.4e38f;
        dB[s][0] = 3.4e38f; dB[s][1] = 3.4e38f;
    }

    #pragma unroll 2
    for (int j = 0; j < CSPLIT_A; j += 4) {
        #pragma unroll
        for (int s = 0; s < 4; s++) {
            float4 c = cand[j + s];
            float ddA = reduced_d(qAx, qAy, qAz, c);
            dA[s][1] = __builtin_amdgcn_fmed3f(dA[s][0], dA[s][1], ddA);
            dA[s][0] = fminf(dA[s][0], ddA);
            float ddB = reduced_d(qBx, qBy, qBz, c);
            dB[s][1] = __builtin_amdgcn_fmed3f(dB[s][0], dB[s][1], ddB);
            dB[s][0] = fminf(dB[s][0], ddB);
        }
    }

    float* __restrict__ rowA = partd + (((size_t)bb * NSPLIT_A + sp) * NPTS + iA) * 8;
    float* __restrict__ rowB = partd + (((size_t)bb * NSPLIT_A + sp) * NPTS + iB) * 8;
    *(float4*)&rowA[0] = make_float4(dA[0][0], dA[0][1], dA[1][0], dA[1][1]);
    *(float4*)&rowA[4] = make_float4(dA[2][0], dA[2][1], dA[3][0], dA[3][1]);
    *(float4*)&rowB[0] = make_float4(dB[0][0], dB[0][1], dB[1][0], dB[1][1]);
    *(float4*)&rowB[4] = make_float4(dB[2][0], dB[2][1], dB[3][0], dB[3][1]);
}

// ---------------------------------------------------------------------------
// Kernel 2b: merge retained values -> conservative threshold (reduced space).
// ---------------------------------------------------------------------------
__global__ __launch_bounds__(256) void knnM_kernel(
    const float* __restrict__ partd,
    float* __restrict__ thr)
{
    const int gid = blockIdx.x * 256 + threadIdx.x;
    const int bb  = gid >> 13;
    const int i   = gid & (NPTS - 1);

    float d[16];
    #pragma unroll
    for (int s = 0; s < 16; s++) d[s] = 3.4e38f;

    for (int sp = 0; sp < NSPLIT_A; sp++) {
        const float* __restrict__ r = partd + (((size_t)bb * NSPLIT_A + sp) * NPTS + i) * 8;
        float4 v0 = *(const float4*)&r[0];
        float4 v1 = *(const float4*)&r[4];
        INSERTD(v0.x); INSERTD(v0.y); INSERTD(v0.z); INSERTD(v0.w);
        INSERTD(v1.x); INSERTD(v1.y); INSERTD(v1.z); INSERTD(v1.w);
    }
    thr[gid] = d[15] + (4e-5f + 1e-5f * fabsf(d[15]));
}

// ---------------------------------------------------------------------------
// Kernel 2c: threshold re-scan (reduced metric) — 1 query/thread, split dim
// in the grid. grid (NPTS/256, NSPLIT_B, NB), block 256.
// ---------------------------------------------------------------------------
__global__ __launch_bounds__(256) void knnB_kernel(
    const float* __restrict__ p,
    const float* __restrict__ thr,
    int* __restrict__ pidx,
    unsigned* __restrict__ pcnt)
{
    const int bb = blockIdx.z, sp = blockIdx.y, q0 = blockIdx.x * 256;
    const int t  = threadIdx.x;

    __shared__ float4 cand[CSPLIT_B];
    const float* __restrict__ pc = p + ((size_t)bb * NPTS + sp * CSPLIT_B) * 3;
    for (int j = t; j < CSPLIT_B; j += 256) {
        float cx = pc[j * 3 + 0], cy = pc[j * 3 + 1], cz = pc[j * 3 + 2];
        float s  = fmaf(cx, cx, fmaf(cy, cy, cz * cz));
        cand[j] = make_float4(cx, cy, cz, s);
    }
    __syncthreads();

    const int i = q0 + t;
    const float qx = p[((size_t)bb * NPTS + i) * 3 + 0];
    const float qy = p[((size_t)bb * NPTS + i) * 3 + 1];
    const float qz = p[((size_t)bb * NPTS + i) * 3 + 2];
    const float thv = thr[bb * NPTS + i];

    int cnt = 0;
    int* __restrict__ row = pidx + (((size_t)bb * NSPLIT_B + sp) * NPTS + i) * 16;
    #pragma unroll 4
    for (int j = 0; j < CSPLIT_B; j++) {
        float dd = reduced_d(qx, qy, qz, cand[j]);
        if (dd <= thv) {
            if (cnt < 16) row[cnt] = sp * CSPLIT_B + j;
            cnt++;
        }
    }
    pcnt[((size_t)bb * NSPLIT_B + sp) * NPTS + i] = (unsigned)cnt;
}

// ---------------------------------------------------------------------------
// Kernel 2d: finalize.
// ---------------------------------------------------------------------------
__global__ __launch_bounds__(256) void knnF_kernel(
    const float* __restrict__ p,
    const int* __restrict__ pidx,
    const unsigned* __restrict__ pcnt,
    int* __restrict__ knn_idx)
{
    const int gid = blockIdx.x * 256 + threadIdx.x;
    const int bb  = gid >> 13;
    const int i   = gid & (NPTS - 1);

    int cnts[NSPLIT_B];
    int total = 0, mx = 0;
    #pragma unroll
    for (int sp = 0; sp < NSPLIT_B; sp++) {
        cnts[sp] = (int)pcnt[((size_t)bb * NSPLIT_B + sp) * NPTS + i];
        total += cnts[sp];
        mx = max(mx, cnts[sp]);
    }
    int* __restrict__ out = knn_idx + (size_t)gid * 16;

    if (mx <= 16 && total == 16) {
        int w = 0;
        for (int sp = 0; sp < NSPLIT_B; sp++) {
            const int* __restrict__ r = pidx + (((size_t)bb * NSPLIT_B + sp) * NPTS + i) * 16;
            for (int e = 0; e < cnts[sp]; e++) out[w++] = r[e];
        }
        return;
    }

    const float qx = p[((size_t)bb * NPTS + i) * 3 + 0];
    const float qy = p[((size_t)bb * NPTS + i) * 3 + 1];
    const float qz = p[((size_t)bb * NPTS + i) * 3 + 2];
    const float sqi = __fadd_rn(__fadd_rn(__fmul_rn(qx, qx), __fmul_rn(qy, qy)),
                                __fmul_rn(qz, qz));
    float ld[16];
    int   li[16];
    #pragma unroll
    for (int s = 0; s < 16; s++) { ld[s] = 3.4e38f; li[s] = 0; }

    if (mx <= 16) {
        for (int sp = 0; sp < NSPLIT_B; sp++) {
            const int* __restrict__ r = pidx + (((size_t)bb * NSPLIT_B + sp) * NPTS + i) * 16;
            for (int e = 0; e < cnts[sp]; e++) {
                int j = r[e];
                float cx = p[((size_t)bb * NPTS + j) * 3 + 0];
                float cy = p[((size_t)bb * NPTS + j) * 3 + 1];
                float cz = p[((size_t)bb * NPTS + j) * 3 + 2];
                float sqj = __fadd_rn(__fadd_rn(__fmul_rn(cx, cx), __fmul_rn(cy, cy)),
                                      __fmul_rn(cz, cz));
                float dot = __fadd_rn(__fadd_rn(__fmul_rn(qx, cx), __fmul_rn(qy, cy)),
                                      __fmul_rn(qz, cz));
                float d2 = __fsub_rn(__fadd_rn(sqi, sqj), __fmul_rn(2.0f, dot));
                INSERT16(d2, j);
            }
        }
    } else {
        for (int j = 0; j < NPTS; j++) {
            float cx = p[((size_t)bb * NPTS + j) * 3 + 0];
            float cy = p[((size_t)bb * NPTS + j) * 3 + 1];
            float cz = p[((size_t)bb * NPTS + j) * 3 + 2];
            float sqj = __fadd_rn(__fadd_rn(__fmul_rn(cx, cx), __fmul_rn(cy, cy)),
                                  __fmul_rn(cz, cz));
            float dot = __fadd_rn(__fadd_rn(__fmul_rn(qx, cx), __fmul_rn(qy, cy)),
                                  __fmul_rn(qz, cz));
            float d2 = __fsub_rn(__fadd_rn(sqi, sqj), __fmul_rn(2.0f, dot));
            INSERT16(d2, j);
        }
    }
    #pragma unroll
    for (int s = 0; s < 16; s++) out[s] = li[s];
}

// ---------------------------------------------------------------------------
// Kernel 3: fused PE-MLP + attention MLP (bf16 MFMA) + softmax + weighted sum.
// The r12-verified version: 8 points/block, bf16 kTb+vTb gathers, bn1 fold,
// XCD swizzle. grid (NPTS/8, NB), block 256.
// ---------------------------------------------------------------------------
__global__ __launch_bounds__(256) void attn_kernel(
    const float* __restrict__ p,
    const float* __restrict__ qT, const unsigned short* __restrict__ kTb,
    const unsigned short* __restrict__ vTb,
    const int*   __restrict__ knn_idx,
    const float* __restrict__ pe_w1,
    const float* __restrict__ pe_bn_g, const float* __restrict__ pe_bn_b,
    const float* __restrict__ pe_bn_m, const float* __restrict__ pe_bn_v,
    const float* __restrict__ pe_w2, const float* __restrict__ pe_b2,
    const float* __restrict__ bn1g, const float* __restrict__ bn1b,
    const float* __restrict__ bn1m, const float* __restrict__ bn1v,
    const float* __restrict__ at_w1,
    const float* __restrict__ bn2g, const float* __restrict__ bn2b,
    const float* __restrict__ bn2m, const float* __restrict__ bn2v,
    const float* __restrict__ at_w2, const float* __restrict__ at_b2,
    float* __restrict__ y)
{
    const int bx = (blockIdx.x & 7) * (NPTS / 8 / 8) + (blockIdx.x >> 3);
    const int bb = blockIdx.y;
    const int i0 = bx * 8;
    const int t  = threadIdx.x;
    const int w  = t >> 6;
    const int l  = t & 63;
    const int lm = t & 15;
    const int lq = l >> 4;

    __shared__ __align__(16) unsigned short a1s[128 * 128];
    __shared__ __align__(16) float hbuf[3][128];
    __shared__ __align__(16) int   nidx[128];
    __shared__ __align__(16) float sc1[128], sh1[128], sc2[128], sh2[128];
    __shared__ __align__(16) float pw2t[3][128], pb2s[128], ab2s[128];

    float* __restrict__ ybuf = (float*)a1s;

    if (t < 128) {
        int c = t;
        float s1 = bn1g[c] / sqrtf(bn1v[c] + BN_EPS);
        sc1[c] = s1; sh1[c] = bn1b[c] - bn1m[c] * s1;
        float s2 = bn2g[c] / sqrtf(bn2v[c] + BN_EPS);
        sc2[c] = s2; sh2[c] = bn2b[c] - bn2m[c] * s2;
        pw2t[0][c] = pe_w2[c * 3 + 0];
        pw2t[1][c] = pe_w2[c * 3 + 1];
        pw2t[2][c] = pe_w2[c * 3 + 2];
        pb2s[c] = pe_b2[c];
        ab2s[c] = at_b2[c];
    } else {
        int e = t - 128;
        nidx[e] = knn_idx[(bb * NPTS + i0 + (e >> 4)) * 16 + (e & 15)];
    }
    __syncthreads();

    if (t < 128) {
        int pt = t >> 4;
        int j = nidx[t];
        float pix = p[((size_t)bb * NPTS + i0 + pt) * 3 + 0];
        float piy = p[((size_t)bb * NPTS + i0 + pt) * 3 + 1];
        float piz = p[((size_t)bb * NPTS + i0 + pt) * 3 + 2];
        float rx = p[((size_t)bb * NPTS + j) * 3 + 0] - pix;
        float ry = p[((size_t)bb * NPTS + j) * 3 + 1] - piy;
        float rz = p[((size_t)bb * NPTS + j) * 3 + 2] - piz;
        #pragma unroll
        for (int o = 0; o < 3; o++) {
            float hv = pe_w1[o * 3 + 0] * rx + pe_w1[o * 3 + 1] * ry + pe_w1[o * 3 + 2] * rz;
            float sc = pe_bn_g[o] / sqrtf(pe_bn_v[o] + BN_EPS);
            float sh = pe_bn_b[o] - pe_bn_m[o] * sc;
            hbuf[o][t] = fmaxf(hv * sc + sh, 0.0f);
        }
    }
    __syncthreads();

    // ---- phase 1: a1 = relu(q' - k' + nr') -> bf16 LDS (swizzled) ----
    {
        const int c0 = 2 * l, c1 = 2 * l + 1;
        const float s1a = sc1[c0], s1b = sc1[c1];
        const float pa0 = pw2t[0][c0] * s1a, pa1 = pw2t[1][c0] * s1a, pa2 = pw2t[2][c0] * s1a;
        const float pda = pb2s[c0] * s1a + sh1[c0];
        const float pb0 = pw2t[0][c1] * s1b, pb1 = pw2t[1][c1] * s1b, pb2_ = pw2t[2][c1] * s1b;
        const float pdb = pb2s[c1] * s1b + sh1[c1];
        unsigned* a1u = (unsigned*)a1s;
        for (int it = 0; it < 32; ++it) {
            int col = w + 4 * it;
            int pt  = col >> 4;
            int j   = nidx[col];
            float2 qv2 = *(const float2*)&qT[((size_t)(bb * NPTS + i0 + pt)) * NC + c0];
            unsigned ku = *(const unsigned*)&kTb[((size_t)(bb * NPTS + j)) * NC + c0];
            float k0 = __uint_as_float(ku << 16);
            float k1 = __uint_as_float(ku & 0xffff0000u);
            float h0 = hbuf[0][col], h1 = hbuf[1][col], h2 = hbuf[2][col];
            float nra = fmaf(pa0, h0, fmaf(pa1, h1, fmaf(pa2, h2, pda)));
            float nrb = fmaf(pb0, h0, fmaf(pb1, h1, fmaf(pb2_, h2, pdb)));
            float a0 = fmaxf(qv2.x - k0 + nra, 0.0f);
            float a1v = fmaxf(qv2.y - k1 + nrb, 0.0f);
            a1u[col * 64 + (l ^ ((col & 7) << 2))] = pack2bf(a0, a1v);
        }
    }

    v8s wf[2][4];
    #pragma unroll
    for (int rt = 0; rt < 2; rt++)
        #pragma unroll
        for (int ks = 0; ks < 4; ks++)
            wf[rt][ks] = load_wfrag_bf16(at_w1 + (size_t)(w * 32 + rt * 16 + lm) * NC + ks * 32 + lq * 8);

    __syncthreads();

    v4f acc[2][8];
    #pragma unroll
    for (int rt = 0; rt < 2; rt++)
        #pragma unroll
        for (int ct = 0; ct < 8; ct++) acc[rt][ct] = (v4f)0.0f;

    #pragma unroll
    for (int ct = 0; ct < 8; ct++) {
        const int col = ct * 16 + lm;
        const int sw8 = (col & 7) << 3;
        #pragma unroll
        for (int ks = 0; ks < 4; ks++) {
            v8s b = *(const v8s*)&a1s[col * 128 + ((ks * 32 + lq * 8) ^ sw8)];
            acc[0][ct] = __builtin_amdgcn_mfma_f32_16x16x32_bf16(wf[0][ks], b, acc[0][ct], 0, 0, 0);
            acc[1][ct] = __builtin_amdgcn_mfma_f32_16x16x32_bf16(wf[1][ks], b, acc[1][ct], 0, 0, 0);
        }
    }
    __syncthreads();

    #pragma unroll
    for (int rt = 0; rt < 2; rt++) {
        const int r0 = w * 32 + rt * 16 + lq * 4;
        float4 scv = *(const float4*)&sc2[r0];
        float4 shv = *(const float4*)&sh2[r0];
        #pragma unroll
        for (int ct = 0; ct < 8; ct++) {
            const int col = ct * 16 + lm;
            v4f v = acc[rt][ct];
            float x0 = fmaxf(v[0] * scv.x + shv.x, 0.0f);
            float x1 = fmaxf(v[1] * scv.y + shv.y, 0.0f);
            float x2 = fmaxf(v[2] * scv.z + shv.z, 0.0f);
            float x3 = fmaxf(v[3] * scv.w + shv.w, 0.0f);
            *(uint2*)&a1s[col * 128 + (r0 ^ ((col & 7) << 3))] =
                make_uint2(pack2bf(x0, x1), pack2bf(x2, x3));
        }
    }

    #pragma unroll
    for (int rt = 0; rt < 2; rt++)
        #pragma unroll
        for (int ks = 0; ks < 4; ks++)
            wf[rt][ks] = load_wfrag_bf16(at_w2 + (size_t)(w * 32 + rt * 16 + lm) * NC + ks * 32 + lq * 8);

    __syncthreads();

    #pragma unroll
    for (int rt = 0; rt < 2; rt++)
        #pragma unroll
        for (int ct = 0; ct < 8; ct++) acc[rt][ct] = (v4f)0.0f;

    #pragma unroll
    for (int ct = 0; ct < 8; ct++) {
        const int col = ct * 16 + lm;
        const int sw8 = (col & 7) << 3;
        #pragma unroll
        for (int ks = 0; ks < 4; ks++) {
            v8s b = *(const v8s*)&a1s[col * 128 + ((ks * 32 + lq * 8) ^ sw8)];
            acc[0][ct] = __builtin_amdgcn_mfma_f32_16x16x32_bf16(b, wf[0][ks], acc[0][ct], 0, 0, 0);
            acc[1][ct] = __builtin_amdgcn_mfma_f32_16x16x32_bf16(b, wf[1][ks], acc[1][ct], 0, 0, 0);
        }
    }
    __syncthreads();

    #pragma unroll
    for (int ct = 0; ct < 8; ct++) {
        const int colb = ct * 16 + lq * 4;
        float4 h0 = *(const float4*)&hbuf[0][colb];
        float4 h1 = *(const float4*)&hbuf[1][colb];
        float4 h2 = *(const float4*)&hbuf[2][colb];
        int j0 = nidx[colb + 0], j1 = nidx[colb + 1];
        int j2 = nidx[colb + 2], j3 = nidx[colb + 3];
        #pragma unroll
        for (int rt = 0; rt < 2; rt++) {
            const int c = w * 32 + rt * 16 + lm;
            const float pw0 = pw2t[0][c], pw1 = pw2t[1][c], pw2v = pw2t[2][c];
            const float pb = pb2s[c], b2 = ab2s[c];
            v4f lg = acc[rt][ct];
            float v0 = bf16_to_f32(vTb[((size_t)(bb * NPTS + j0)) * NC + c]);
            float v1 = bf16_to_f32(vTb[((size_t)(bb * NPTS + j1)) * NC + c]);
            float v2 = bf16_to_f32(vTb[((size_t)(bb * NPTS + j2)) * NC + c]);
            float v3 = bf16_to_f32(vTb[((size_t)(bb * NPTS + j3)) * NC + c]);
            float e0 = __expf(lg[0] + b2);
            float e1 = __expf(lg[1] + b2);
            float e2 = __expf(lg[2] + b2);
            float e3 = __expf(lg[3] + b2);
            float n0 = pw0 * h0.x + pw1 * h1.x + pw2v * h2.x + pb;
            float n1 = pw0 * h0.y + pw1 * h1.y + pw2v * h2.y + pb;
            float n2 = pw0 * h0.z + pw1 * h1.z + pw2v * h2.z + pb;
            float n3 = pw0 * h0.w + pw1 * h1.w + pw2v * h2.w + pb;
            float se = (e0 + e1) + (e2 + e3);
            float pr = (e0 * (v0 + n0) + e1 * (v1 + n1)) + (e2 * (v2 + n2) + e3 * (v3 + n3));
            se += __shfl_xor(se, 16); pr += __shfl_xor(pr, 16);
            se += __shfl_xor(se, 32); pr += __shfl_xor(pr, 32);
            if (lq == 0) ybuf[c * 12 + ct] = pr / se;
        }
    }
    __syncthreads();

    {
        int c = t >> 1, half = t & 1;
        float4 o = *(const float4*)&ybuf[c * 12 + half * 4];
        *(float4*)&y[((size_t)bb * NC + c) * NPTS + i0 + half * 4] = o;
    }
}

// ---------------------------------------------------------------------------
extern "C" void kernel_launch(void* const* d_in, const int* in_sizes, int n_in,
                              void* d_out, int out_size, void* d_ws, size_t ws_size,
                              hipStream_t stream) {
    const float* p     = (const float*)d_in[0];
    const float* x     = (const float*)d_in[1];
    const float* wq    = (const float*)d_in[2];
    const float* bq    = (const float*)d_in[3];
    const float* wk    = (const float*)d_in[4];
    const float* bk    = (const float*)d_in[5];
    const float* wv    = (const float*)d_in[6];
    const float* bv    = (const float*)d_in[7];
    const float* pe_w1 = (const float*)d_in[8];
    const float* pe_bn_g = (const float*)d_in[9];
    const float* pe_bn_b = (const float*)d_in[10];
    const float* pe_bn_m = (const float*)d_in[11];
    const float* pe_bn_v = (const float*)d_in[12];
    const float* pe_w2 = (const float*)d_in[13];
    const float* pe_b2 = (const float*)d_in[14];
    const float* bn1g  = (const float*)d_in[15];
    const float* bn1b  = (const float*)d_in[16];
    const float* bn1m  = (const float*)d_in[17];
    const float* bn1v  = (const float*)d_in[18];
    const float* at_w1 = (const float*)d_in[19];
    const float* bn2g  = (const float*)d_in[20];
    const float* bn2b  = (const float*)d_in[21];
    const float* bn2m  = (const float*)d_in[22];
    const float* bn2v  = (const float*)d_in[23];
    const float* at_w2 = (const float*)d_in[24];
    const float* at_b2 = (const float*)d_in[25];
    float* out = (float*)d_out;

    // workspace (25 MB): [idx 1MB][X: 24MB]
    //   final tensors (written by qkv, after ALL kNN kernels):
    //     qT  fp32 @ X (8MB, s1-scaled) | kTb bf16 @ X+8MB (4MB, s1-scaled)
    //     vTb bf16 @ X+12MB (4MB)
    //   kNN scratch (all consumed before qkv):
    //     partd @ X (16.8MB) | pidx @ X (16.8MB, after knnM) |
    //     pcnt @ X+18MB (1.05MB) | thr @ X+22MB (64KB)
    char* base = (char*)d_ws;
    int*   idx   = (int*)base;
    char*  X     = base + (1u << 20);
    float* qT    = (float*)X;
    unsigned short* kTb = (unsigned short*)(X + (size_t)8 * (1u << 20));
    unsigned short* vTb = (unsigned short*)(X + (size_t)12 * (1u << 20));
    float* partd = (float*)X;
    int*   pidx  = (int*)X;
    unsigned* pcnt = (unsigned*)(X + (size_t)18 * (1u << 20));
    float* thr   = (float*)(X + (size_t)22 * (1u << 20));

    knnA_kernel<<<dim3(NPTS / 512, NSPLIT_A, NB), 256, 0, stream>>>(p, partd);
    knnM_kernel<<<dim3(NB * NPTS / 256), 256, 0, stream>>>(partd, thr);
    knnB_kernel<<<dim3(NPTS / 256, NSPLIT_B, NB), 256, 0, stream>>>(p, thr, pidx, pcnt);
    knnF_kernel<<<dim3(NB * NPTS / 256), 256, 0, stream>>>(p, pidx, pcnt, idx);
    qkv_kernel<<<dim3(NPTS / 64, NB), 256, 0, stream>>>(
        x, wq, bq, wk, bk, wv, bv, bn1g, bn1v, qT, kTb, vTb);
    attn_kernel<<<dim3(NPTS / 8, NB), 256, 0, stream>>>(
        p, qT, kTb, vTb, idx,
        pe_w1, pe_bn_g, pe_bn_b, pe_bn_m, pe_bn_v, pe_w2, pe_b2,
        bn1g, bn1b, bn1m, bn1v, at_w1,
        bn2g, bn2b, bn2m, bn2v, at_w2, at_b2, out);
}